// Round 18
// baseline (84.183 us; speedup 1.0000x reference)
//
#include <hip/hip_runtime.h>

#define P_N 40000
#define M_N 100
#define NBF 10000   // k_fused blocks: 2 waves/block, 2 pillars/wave
#define NPART 80    // per-bucket stats: [0..44]=M2 corr, [45..53]=M1, [64..73]=R2 raw
#define NUSED 74
#define NBUCKET 32

typedef _Float16 half2_t __attribute__((ext_vector_type(2)));
typedef _Float16 half8_t __attribute__((ext_vector_type(8)));
typedef float    f32x16 __attribute__((ext_vector_type(16)));

__device__ __forceinline__ float bcf(int x) { return __int_as_float(x); }
__device__ __forceinline__ int   bci(float x) { return __float_as_int(x); }
__device__ __forceinline__ float rlf(float v, int l) {
  return bcf(__builtin_amdgcn_readlane(bci(v), l));
}
__device__ __forceinline__ int pk16i(float a, float b) {
  return __builtin_bit_cast(int, __builtin_amdgcn_cvt_pkrtz(a, b));
}
__device__ __forceinline__ half2_t h2(int x) { return __builtin_bit_cast(half2_t, x); }
__device__ __forceinline__ half8_t h8(int4 v) { return __builtin_bit_cast(half8_t, v); }
__device__ __forceinline__ float dot2(int a, int b, float acc) {
  return __builtin_amdgcn_fdot2(h2(a), h2(b), acc, false);
}

// DPP full-wave64 add-reduce on the VALU pipe. Lane 63 holds the sum.
__device__ __forceinline__ float dpp_sum64(float x) {
  x += bcf(__builtin_amdgcn_update_dpp(0, bci(x), 0x111, 0xf, 0xf, true)); // row_shr:1
  x += bcf(__builtin_amdgcn_update_dpp(0, bci(x), 0x112, 0xf, 0xf, true)); // row_shr:2
  x += bcf(__builtin_amdgcn_update_dpp(0, bci(x), 0x114, 0xf, 0xf, true)); // row_shr:4
  x += bcf(__builtin_amdgcn_update_dpp(0, bci(x), 0x118, 0xf, 0xf, true)); // row_shr:8
  x += bcf(__builtin_amdgcn_update_dpp(0, bci(x), 0x142, 0xf, 0xf, true)); // row_bcast:15
  x += bcf(__builtin_amdgcn_update_dpp(0, bci(x), 0x143, 0xf, 0xf, true)); // row_bcast:31
  return x;
}

// ---------------- Kernel 0: zero the atomic buckets ----------------

__global__ __launch_bounds__(256) void k_zero(float* __restrict__ buckets) {
  const int i = threadIdx.x;
  #pragma unroll
  for (int k = 0; k < NBUCKET * NPART / 256; ++k) buckets[k * 256 + i] = 0.f;
}

// ---------------- Kernel 1 (fused) ----------------
// Moments: mean-expansion (verified r15) — 10 raw products + lane-indexed corr.
// umax: MFMA — per pillar u'[128 pts x 64 ch] via 8x mfma_f32_32x32x16_f16
// (A: 32 pts x K16, k0..3 = x,y,z,i, lanes 0..31; B: wave-constant weights).
// Invalid point slots staged as f16 qNaN -> maxnum merges drop them.
// umax_d = sE_d + colmax. Epilogue: bucketed atomicAdd (r17).

__global__ __launch_bounds__(128) void k_fused(
    const float* __restrict__ px, const float* __restrict__ py,
    const float* __restrict__ pz, const float* __restrict__ pi,
    const int* __restrict__ npp, const int* __restrict__ coors,
    const float* __restrict__ W,
    float* __restrict__ buckets, float* __restrict__ umm)
{
  const int lane = threadIdx.x & 63;
  const int wid  = threadIdx.x >> 6;    // 0..1
  const int d    = lane;

  __shared__ int4  stage[2][2][64];     // [wave][pillar][lane] = 2 point-major packs
  __shared__ float red[2][NPART];

  // ---- per-lane statistic assignment ----
  int c = 9, c2 = 9;                    // sentinel (lanes >= 54 idle)
  if (lane < 45) {
    int k = lane; c = 0;
    while (k >= 9 - c) { k -= 9 - c; ++c; }
    c2 = c + k;
  } else if (lane < 54) {
    c = lane - 45; c2 = 9;              // M1: pair with constant-1 feature
  }
  const int rc1 = (c  < 4) ? c  : (c  < 7) ? c  - 4 : (c  < 9) ? c  - 2 : 4;
  const int rc2 = (c2 < 4) ? c2 : (c2 < 7) ? c2 - 4 : (c2 < 9) ? c2 - 2 : 4;
  const bool bothVec = (rc1 < 4) && (rc2 < 4);
  const bool statln  = lane < 54;

  float w[9];
  #pragma unroll
  for (int q = 0; q < 9; ++q) w[q] = W[q * 64 + d];
  const float sA = w[0] + w[4], sB = w[1] + w[5], sC = w[2] + w[6], sD = w[3];
  const int H1 = 0x3C003C00;            // (1.0h, 1.0h)

  // ---- wave-constant MFMA B fragments (channels 32j..32j+31) ----
  const int pAB = pk16i(sA, sB);
  const int pCD = pk16i(sC, sD);
  const bool lo32 = lane < 32;
  half8_t Bf[2];
  #pragma unroll
  for (int j = 0; j < 2; ++j) {
    const int src = 32 * j + (lane & 31);
    const int b0 = __shfl(pAB, src);
    const int b1 = __shfl(pCD, src);
    Bf[j] = h8(make_int4(lo32 ? b0 : 0, lo32 ? b1 : 0, 0, 0));
  }
  const f32x16 Z16 = (f32x16)0.0f;

  const bool act = lane < 50;
  const int wgid  = blockIdx.x * 2 + wid;
  const int pbase = __builtin_amdgcn_readfirstlane(wgid * 2);

  const int2 n2 = ((const int2*)npp)[wgid];
  int4 cc[2];
  cc[0] = ((const int4*)coors)[pbase + 0];
  cc[1] = ((const int4*)coors)[pbase + 1];

  // ---- load rows, pack f16; stage point-major (NaN-masked) for MFMA ----
  int u0[2], u1[2], u2[2], u3[2];
  #pragma unroll
  for (int it = 0; it < 2; ++it) {
    const int p_ = pbase + it;
    const int n_ = ((const int*)&n2)[it];
    float2 X = make_float2(0.f, 0.f), Y = X, Z = X, I = X;
    if (act) {
      X = ((const float2*)(px + (size_t)p_ * M_N))[lane];
      Y = ((const float2*)(py + (size_t)p_ * M_N))[lane];
      Z = ((const float2*)(pz + (size_t)p_ * M_N))[lane];
      I = ((const float2*)(pi + (size_t)p_ * M_N))[lane];
    }
    u0[it] = pk16i(X.x, X.y);            // feature-major (slot0, slot1) for moments
    u1[it] = pk16i(Y.x, Y.y);
    u2[it] = pk16i(Z.x, Z.y);
    u3[it] = pk16i(I.x, I.y);
    const int NN = 0x7E007E00;           // (qNaN, qNaN) f16
    const bool v0 = (2 * lane)     < n_;
    const bool v1 = (2 * lane + 1) < n_;
    int4 pm;                             // point-major: (x,y),(z,i) per point
    pm.x = v0 ? pk16i(X.x, Y.x) : NN;
    pm.y = v0 ? pk16i(Z.x, I.x) : NN;
    pm.z = v1 ? pk16i(X.y, Y.y) : NN;
    pm.w = v1 ? pk16i(Z.y, I.y) : NN;
    stage[wid][it][lane] = pm;
  }

  float R2a[10] = {};
  float corrAcc = 0.f;

  #pragma unroll
  for (int it = 0; it < 2; ++it) {
    const int p_ = pbase + it;
    const int n  = ((const int*)&n2)[it];
    const float nf = (float)n;

    // validity mask for this lane's two point slots
    const unsigned msk = ((2 * lane     < n) ? 0x0000FFFFu : 0u)
                       | ((2 * lane + 1 < n) ? 0xFFFF0000u : 0u);
    const int g0 = u0[it] & msk;
    const int g1 = u1[it] & msk;
    const int g2 = u2[it] & msk;
    const int g3 = u3[it] & msk;

    // full sums (means) + valid sums: 7 DPP chains
    float fx = dot2(u0[it], H1, 0.f);
    float fy = dot2(u1[it], H1, 0.f);
    float fz = dot2(u2[it], H1, 0.f);
    float vx = dot2(g0, H1, 0.f);
    float vy = dot2(g1, H1, 0.f);
    float vz = dot2(g2, H1, 0.f);
    float vi = dot2(g3, H1, 0.f);
    fx = dpp_sum64(fx); fy = dpp_sum64(fy); fz = dpp_sum64(fz);
    vx = dpp_sum64(vx); vy = dpp_sum64(vy); vz = dpp_sum64(vz); vi = dpp_sum64(vi);

    const int nc = n < 1 ? 1 : n;
    const float inv = __builtin_amdgcn_rcpf((float)nc);
    const float mx = rlf(fx, 63) * inv;
    const float my = rlf(fy, 63) * inv;
    const float mz = rlf(fz, 63) * inv;
    const float svx = rlf(vx, 63);
    const float svy = rlf(vy, 63);
    const float svz = rlf(vz, 63);
    const float svi = rlf(vi, 63);

    const float xb = fmaf((float)cc[it].w, 0.16f, 0.08f);            // X0 = 0
    const float yb = fmaf((float)cc[it].z, 0.16f, 0.08f - 39.68f);   // Y0 = -39.68

    // 10 global raw products among x,y,z,i (valid-masked)
    R2a[0] = dot2(g0, g0, R2a[0]);
    R2a[1] = dot2(g0, g1, R2a[1]);
    R2a[2] = dot2(g0, g2, R2a[2]);
    R2a[3] = dot2(g0, g3, R2a[3]);
    R2a[4] = dot2(g1, g1, R2a[4]);
    R2a[5] = dot2(g1, g2, R2a[5]);
    R2a[6] = dot2(g1, g3, R2a[6]);
    R2a[7] = dot2(g2, g2, R2a[7]);
    R2a[8] = dot2(g2, g3, R2a[8]);
    R2a[9] = dot2(g3, g3, R2a[9]);

    // per-lane correction term
    {
      const float nxb = nf * xb, nyb = nf * yb;
      const float S1 = (rc1 == 0) ? svx : (rc1 == 1) ? svy : (rc1 == 2) ? svz
                     : (rc1 == 3) ? svi : (rc1 == 4) ? nf  : (rc1 == 5) ? nxb : nyb;
      const float S2 = (rc2 == 0) ? svx : (rc2 == 1) ? svy : (rc2 == 2) ? svz
                     : (rc2 == 3) ? svi : (rc2 == 4) ? nf  : (rc2 == 5) ? nxb : nyb;
      float base = 0.f;
      if (!bothVec)
        base = (rc1 > 3) ? ((rc1 == 4) ? S2 : (rc1 == 5) ? xb * S2 : yb * S2)
                         : ((rc2 == 4) ? S1 : (rc2 == 5) ? xb * S1 : yb * S1);
      const float mv1 = (c  == 4) ? mx : (c  == 5) ? my : (c  == 6) ? mz : 0.f;
      const float mv2 = (c2 == 4) ? mx : (c2 == 5) ? my : (c2 == 6) ? mz : 0.f;
      const float term = base - mv1 * S2 - mv2 * S1 + nf * mv1 * mv2;
      if (statln) corrAcc += term;
    }

    // per-pillar constant term of the linear output (added post-max)
    const float sE = fmaf(-mx, w[4], fmaf(-my, w[5], fmaf(-mz, w[6],
                     fmaf(xb, w[7], yb * w[8]))));

    // ---- umax via MFMA: 4 M-tiles x 2 N-tiles of 32x32x16 f16 ----
    const int2* sp2 = (const int2*)&stage[wid][it][0];   // 128 point slots
    f32x16 R0, R1;
    #pragma unroll
    for (int t = 0; t < 4; ++t) {
      int2 pa = make_int2(0, 0);
      if (lo32) pa = sp2[32 * t + (lane & 31)];
      const half8_t A = h8(make_int4(pa.x, pa.y, 0, 0));
      const f32x16 c0 = __builtin_amdgcn_mfma_f32_32x32x16_f16(A, Bf[0], Z16, 0, 0, 0);
      const f32x16 c1 = __builtin_amdgcn_mfma_f32_32x32x16_f16(A, Bf[1], Z16, 0, 0, 0);
      if (t == 0) { R0 = c0; R1 = c1; }
      else {
        R0 = __builtin_elementwise_max(R0, c0);   // maxnum: NaN rows drop out
        R1 = __builtin_elementwise_max(R1, c1);
      }
    }
    // fold 16 regs (rows of this lane's half), then merge halves via xor-32
    #pragma unroll
    for (int s = 8; s; s >>= 1) {
      #pragma unroll
      for (int i = 0; i < s; ++i) {
        R0[i] = fmaxf(R0[i], R0[i + s]);
        R1[i] = fmaxf(R1[i], R1[i + s]);
      }
    }
    float m0 = R0[0], m1 = R1[0];
    m0 = fmaxf(m0, __shfl_xor(m0, 32));
    m1 = fmaxf(m1, __shfl_xor(m1, 32));
    const float um = ((lane < 32) ? m0 : m1) + sE;   // channel d = lane
    umm[(size_t)p_ * 64 + d] = um;
  }

  // ---- epilogue: 10 chains for R2, block reduce, bucketed atomicAdd ----
  #pragma unroll
  for (int i = 0; i < 10; ++i) R2a[i] = dpp_sum64(R2a[i]);

  red[wid][lane] = corrAcc;              // lanes >=54 wrote 0
  if (lane == 63) {
    #pragma unroll
    for (int i = 0; i < 10; ++i) red[wid][64 + i] = R2a[i];
  }
  __syncthreads();
  if (threadIdx.x < NUSED) {
    const int t = threadIdx.x;
    atomicAdd(&buckets[(blockIdx.x & (NBUCKET - 1)) * NPART + t],
              red[0][t] + red[1][t]);
  }
}

// ---------------- Kernel 2: buckets -> per-channel BN scale/shift ----------------

__global__ __launch_bounds__(64) void k_stats(
    const float* __restrict__ buckets, const float* __restrict__ W,
    const float* __restrict__ gamma, const float* __restrict__ beta,
    float* __restrict__ scale, float* __restrict__ shift)
{
  const int d = threadIdx.x;
  __shared__ float Cs[NUSED];
  {
    float s0 = 0.f, s1 = 0.f;
    #pragma unroll
    for (int b = 0; b < NBUCKET; ++b) {
      s0 += buckets[b * NPART + d];
      if (d < NUSED - 64) s1 += buckets[b * NPART + 64 + d];
    }
    Cs[d] = s0;
    if (d < NUSED - 64) Cs[64 + d] = s1;
  }
  __syncthreads();

  // assemble mom1[9], mom2[45]
  float mom1[9];
  #pragma unroll
  for (int q = 0; q < 9; ++q) mom1[q] = Cs[45 + q];
  float mom2[45];
  {
    int k = 0;
    #pragma unroll
    for (int cA = 0; cA < 9; ++cA) {
      #pragma unroll
      for (int cB = cA; cB < 9; ++cB) {
        float v = Cs[k];
        if (cA <= 6 && cB <= 6) {
          const int a = (cA < 4) ? cA : cA - 4;
          const int b = (cB < 4) ? cB : cB - 4;
          const int lo = a < b ? a : b;
          const int hi = a < b ? b : a;
          const int idx = lo * 4 - lo * (lo - 1) / 2 + (hi - lo);
          v += Cs[64 + idx];
        }
        mom2[k] = v;
        ++k;
      }
    }
  }

  float w[9];
  #pragma unroll
  for (int q = 0; q < 9; ++q) w[q] = W[q * 64 + d];
  const float invN = 1.f / ((float)P_N * (float)M_N);
  float mu = 0.f;
  #pragma unroll
  for (int q = 0; q < 9; ++q) mu += mom1[q] * w[q];
  mu *= invN;
  float e2 = 0.f;
  int k = 0;
  #pragma unroll
  for (int cA = 0; cA < 9; ++cA) {
    #pragma unroll
    for (int cB = cA; cB < 9; ++cB) {
      const float t = w[cA] * w[cB] * mom2[k];
      e2 += (cA == cB) ? t : 2.f * t;
      ++k;
    }
  }
  e2 *= invN;
  float var = e2 - mu * mu;
  var = var < 0.f ? 0.f : var;
  const float sc = gamma[d] * rsqrtf(var + 1e-5f);
  const float sh = fmaf(-mu, sc, beta[d]);
  scale[d] = sc;
  shift[d] = sh;
}

// ---------------- Kernel 3: finalize in place ----------------

__global__ __launch_bounds__(256) void k_apply(
    const int* __restrict__ npp, const float* __restrict__ scale,
    const float* __restrict__ shift, float* __restrict__ out)
{
  const int gid = blockIdx.x * 256 + threadIdx.x;   // 0 .. P_N*64/4 - 1
  const int p = gid >> 4;
  const int q = gid & 15;

  float4 u4 = ((const float4*)out)[gid];
  const float4 sc4 = ((const float4*)scale)[q];
  const float4 sh4 = ((const float4*)shift)[q];
  const int n = npp[p];
  const bool has_masked = n < M_N;

  float4 r;
  float t;
  t = fmaf(sc4.x, u4.x, sh4.x); if (has_masked) t = fmaxf(t, sh4.x); r.x = fmaxf(t, 0.f);
  t = fmaf(sc4.y, u4.y, sh4.y); if (has_masked) t = fmaxf(t, sh4.y); r.y = fmaxf(t, 0.f);
  t = fmaf(sc4.z, u4.z, sh4.z); if (has_masked) t = fmaxf(t, sh4.z); r.z = fmaxf(t, 0.f);
  t = fmaf(sc4.w, u4.w, sh4.w); if (has_masked) t = fmaxf(t, sh4.w); r.w = fmaxf(t, 0.f);
  ((float4*)out)[gid] = r;
}

// ---------------- launch ----------------

extern "C" void kernel_launch(void* const* d_in, const int* in_sizes, int n_in,
                              void* d_out, int out_size, void* d_ws, size_t ws_size,
                              hipStream_t stream) {
  const float* px    = (const float*)d_in[0];
  const float* py    = (const float*)d_in[1];
  const float* pz    = (const float*)d_in[2];
  const float* pi    = (const float*)d_in[3];
  const int*   npp   = (const int*)d_in[4];
  const int*   coors = (const int*)d_in[5];
  const float* W     = (const float*)d_in[6];
  const float* gamma = (const float*)d_in[7];
  const float* beta  = (const float*)d_in[8];
  float* out = (float*)d_out;

  float* wsf     = (float*)d_ws;
  float* buckets = wsf;                     // NBUCKET*NPART = 2560 floats
  float* scale   = wsf + 2560;              // 64
  float* shift   = wsf + 2624;              // 64

  k_zero<<<1, 256, 0, stream>>>(buckets);
  k_fused<<<NBF, 128, 0, stream>>>(px, py, pz, pi, npp, coors, W, buckets, out);
  k_stats<<<1, 64, 0, stream>>>(buckets, W, gamma, beta, scale, shift);
  k_apply<<<P_N * 64 / 4 / 256, 256, 0, stream>>>(npp, scale, shift, out);
}

// Round 19
// 61.318 us; speedup vs baseline: 1.3729x; 1.3729x over previous
//
#include <hip/hip_runtime.h>

#define P_N 40000
#define M_N 100
#define NBF 10000   // k_fused blocks: 2 waves/block, 2 pillars/wave
#define NPART 80    // per-bucket stats: [0..44]=M2 corr, [45..53]=M1, [64..73]=R2 raw
#define NUSED 74
#define NBUCKET 32

typedef _Float16 half2_t __attribute__((ext_vector_type(2)));

__device__ __forceinline__ float bcf(int x) { return __int_as_float(x); }
__device__ __forceinline__ int   bci(float x) { return __float_as_int(x); }
__device__ __forceinline__ float rlf(float v, int l) {
  return bcf(__builtin_amdgcn_readlane(bci(v), l));
}
__device__ __forceinline__ int pk16i(float a, float b) {
  return __builtin_bit_cast(int, __builtin_amdgcn_cvt_pkrtz(a, b));
}
__device__ __forceinline__ half2_t h2(int x) { return __builtin_bit_cast(half2_t, x); }
__device__ __forceinline__ float dot2(int a, int b, float acc) {
  return __builtin_amdgcn_fdot2(h2(a), h2(b), acc, false);
}

// DPP full-wave64 add-reduce on the VALU pipe. Lane 63 holds the sum.
__device__ __forceinline__ float dpp_sum64(float x) {
  x += bcf(__builtin_amdgcn_update_dpp(0, bci(x), 0x111, 0xf, 0xf, true)); // row_shr:1
  x += bcf(__builtin_amdgcn_update_dpp(0, bci(x), 0x112, 0xf, 0xf, true)); // row_shr:2
  x += bcf(__builtin_amdgcn_update_dpp(0, bci(x), 0x114, 0xf, 0xf, true)); // row_shr:4
  x += bcf(__builtin_amdgcn_update_dpp(0, bci(x), 0x118, 0xf, 0xf, true)); // row_shr:8
  x += bcf(__builtin_amdgcn_update_dpp(0, bci(x), 0x142, 0xf, 0xf, true)); // row_bcast:15
  x += bcf(__builtin_amdgcn_update_dpp(0, bci(x), 0x143, 0xf, 0xf, true)); // row_bcast:31
  return x;
}

// packed u for 2 points from feature-major packs: v_pk_fma_f16 chain.
// NaN in any input half -> NaN in that half's result (dropped by pk_max maxnum).
__device__ __forceinline__ half2_t uPK(int4 q, half2_t AA, half2_t BB,
                                       half2_t CC, half2_t DD, half2_t EE) {
  half2_t t = h2(q.w) * DD + EE;     // i01*DD + EE
  t = h2(q.z) * CC + t;              // + z01*CC
  t = h2(q.y) * BB + t;              // + y01*BB
  t = h2(q.x) * AA + t;              // + x01*AA
  return t;
}

// ---------------- Kernel 0: zero the atomic buckets ----------------

__global__ __launch_bounds__(256) void k_zero(float* __restrict__ buckets) {
  const int i = threadIdx.x;
  #pragma unroll
  for (int k = 0; k < NBUCKET * NPART / 256; ++k) buckets[k * 256 + i] = 0.f;
}

// ---------------- Kernel 1 (fused) ----------------
// Moments: mean-expansion (verified r15) — 10 raw products + lane-indexed corr.
// umax: feature-major f16 packs, NaN-masked invalid slots (maxnum drops NaN),
// BOTH pillars' loops fused: trip = ceil(max(n0,n1)/2), 4 independent
// ds_read+pk_max chains per 2-iter step. Epilogue: bucketed atomicAdd (r17).

__global__ __launch_bounds__(128) void k_fused(
    const float* __restrict__ px, const float* __restrict__ py,
    const float* __restrict__ pz, const float* __restrict__ pi,
    const int* __restrict__ npp, const int* __restrict__ coors,
    const float* __restrict__ W,
    float* __restrict__ buckets, float* __restrict__ umm)
{
  const int lane = threadIdx.x & 63;
  const int wid  = threadIdx.x >> 6;    // 0..1
  const int d    = lane;

  __shared__ int4  stage[2][2][64];     // [wave][pillar][pair] NaN-masked packs
  __shared__ float red[2][NPART];

  // ---- per-lane statistic assignment ----
  int c = 9, c2 = 9;                    // sentinel (lanes >= 54 idle)
  if (lane < 45) {
    int k = lane; c = 0;
    while (k >= 9 - c) { k -= 9 - c; ++c; }
    c2 = c + k;
  } else if (lane < 54) {
    c = lane - 45; c2 = 9;              // M1: pair with constant-1 feature
  }
  const int rc1 = (c  < 4) ? c  : (c  < 7) ? c  - 4 : (c  < 9) ? c  - 2 : 4;
  const int rc2 = (c2 < 4) ? c2 : (c2 < 7) ? c2 - 4 : (c2 < 9) ? c2 - 2 : 4;
  const bool bothVec = (rc1 < 4) && (rc2 < 4);
  const bool statln  = lane < 54;

  float w[9];
  #pragma unroll
  for (int q = 0; q < 9; ++q) w[q] = W[q * 64 + d];
  const float sA = w[0] + w[4], sB = w[1] + w[5], sC = w[2] + w[6], sD = w[3];
  const half2_t AA = h2(pk16i(sA, sA));
  const half2_t BB = h2(pk16i(sB, sB));
  const half2_t CC = h2(pk16i(sC, sC));
  const half2_t DD = h2(pk16i(sD, sD));
  const int H1 = 0x3C003C00;            // (1.0h, 1.0h)

  const bool act = lane < 50;
  const int wgid  = blockIdx.x * 2 + wid;
  const int pbase = __builtin_amdgcn_readfirstlane(wgid * 2);

  const int2 n2 = ((const int2*)npp)[wgid];
  int4 cc[2];
  cc[0] = ((const int4*)coors)[pbase + 0];
  cc[1] = ((const int4*)coors)[pbase + 1];

  // ---- load rows, pack to f16; stage NaN-masked feature-major packs ----
  int u0[2], u1[2], u2[2], u3[2];
  unsigned mskA[2];
  #pragma unroll
  for (int it = 0; it < 2; ++it) {
    const int p_ = pbase + it;
    const int n_ = ((const int*)&n2)[it];
    float2 X = make_float2(0.f, 0.f), Y = X, Z = X, I = X;
    if (act) {
      X = ((const float2*)(px + (size_t)p_ * M_N))[lane];
      Y = ((const float2*)(py + (size_t)p_ * M_N))[lane];
      Z = ((const float2*)(pz + (size_t)p_ * M_N))[lane];
      I = ((const float2*)(pi + (size_t)p_ * M_N))[lane];
    }
    u0[it] = pk16i(X.x, X.y);            // feature-major (slot0, slot1)
    u1[it] = pk16i(Y.x, Y.y);
    u2[it] = pk16i(Z.x, Z.y);
    u3[it] = pk16i(I.x, I.y);
    const unsigned msk = (((2 * lane)     < n_) ? 0x0000FFFFu : 0u)
                       | (((2 * lane + 1) < n_) ? 0xFFFF0000u : 0u);
    mskA[it] = msk;
    const int nm = (int)(0x7E007E00u & ~msk);   // qNaN in invalid halves
    stage[wid][it][lane] = make_int4(u0[it] | nm, u1[it] | nm,
                                     u2[it] | nm, u3[it] | nm);
  }

  float R2a[10] = {};
  float corrAcc = 0.f;
  half2_t EEv[2];

  #pragma unroll
  for (int it = 0; it < 2; ++it) {
    const int n  = ((const int*)&n2)[it];
    const float nf = (float)n;
    const unsigned msk = mskA[it];
    const int g0 = u0[it] & msk;
    const int g1 = u1[it] & msk;
    const int g2 = u2[it] & msk;
    const int g3 = u3[it] & msk;

    // full sums (means) + valid sums: 7 DPP chains
    float fx = dot2(u0[it], H1, 0.f);
    float fy = dot2(u1[it], H1, 0.f);
    float fz = dot2(u2[it], H1, 0.f);
    float vx = dot2(g0, H1, 0.f);
    float vy = dot2(g1, H1, 0.f);
    float vz = dot2(g2, H1, 0.f);
    float vi = dot2(g3, H1, 0.f);
    fx = dpp_sum64(fx); fy = dpp_sum64(fy); fz = dpp_sum64(fz);
    vx = dpp_sum64(vx); vy = dpp_sum64(vy); vz = dpp_sum64(vz); vi = dpp_sum64(vi);

    const int nc = n < 1 ? 1 : n;
    const float inv = __builtin_amdgcn_rcpf((float)nc);
    const float mx = rlf(fx, 63) * inv;
    const float my = rlf(fy, 63) * inv;
    const float mz = rlf(fz, 63) * inv;
    const float svx = rlf(vx, 63);
    const float svy = rlf(vy, 63);
    const float svz = rlf(vz, 63);
    const float svi = rlf(vi, 63);

    const float xb = fmaf((float)cc[it].w, 0.16f, 0.08f);            // X0 = 0
    const float yb = fmaf((float)cc[it].z, 0.16f, 0.08f - 39.68f);   // Y0 = -39.68

    // 10 global raw products among x,y,z,i (valid-masked)
    R2a[0] = dot2(g0, g0, R2a[0]);
    R2a[1] = dot2(g0, g1, R2a[1]);
    R2a[2] = dot2(g0, g2, R2a[2]);
    R2a[3] = dot2(g0, g3, R2a[3]);
    R2a[4] = dot2(g1, g1, R2a[4]);
    R2a[5] = dot2(g1, g2, R2a[5]);
    R2a[6] = dot2(g1, g3, R2a[6]);
    R2a[7] = dot2(g2, g2, R2a[7]);
    R2a[8] = dot2(g2, g3, R2a[8]);
    R2a[9] = dot2(g3, g3, R2a[9]);

    // per-lane correction term
    {
      const float nxb = nf * xb, nyb = nf * yb;
      const float S1 = (rc1 == 0) ? svx : (rc1 == 1) ? svy : (rc1 == 2) ? svz
                     : (rc1 == 3) ? svi : (rc1 == 4) ? nf  : (rc1 == 5) ? nxb : nyb;
      const float S2 = (rc2 == 0) ? svx : (rc2 == 1) ? svy : (rc2 == 2) ? svz
                     : (rc2 == 3) ? svi : (rc2 == 4) ? nf  : (rc2 == 5) ? nxb : nyb;
      float base = 0.f;
      if (!bothVec)
        base = (rc1 > 3) ? ((rc1 == 4) ? S2 : (rc1 == 5) ? xb * S2 : yb * S2)
                         : ((rc2 == 4) ? S1 : (rc2 == 5) ? xb * S1 : yb * S1);
      const float mv1 = (c  == 4) ? mx : (c  == 5) ? my : (c  == 6) ? mz : 0.f;
      const float mv2 = (c2 == 4) ? mx : (c2 == 5) ? my : (c2 == 6) ? mz : 0.f;
      const float term = base - mv1 * S2 - mv2 * S1 + nf * mv1 * mv2;
      if (statln) corrAcc += term;
    }

    // per-pillar constant term of the linear output
    const float sE = fmaf(-mx, w[4], fmaf(-my, w[5], fmaf(-mz, w[6],
                     fmaf(xb, w[7], yb * w[8]))));
    EEv[it] = h2(pk16i(sE, sE));
  }

  // ---- fused umax over BOTH pillars: 4 independent ds_read+pk chains ----
  {
    const int n0 = ((const int*)&n2)[0];
    const int n1 = ((const int*)&n2)[1];
    const int nmax = n0 > n1 ? n0 : n1;
    const int nh = (nmax + 1) >> 1;      // NaN covers odd tails / short pillar
    const int4* sp0 = &stage[wid][0][0];
    const int4* sp1 = &stage[wid][1][0];
    const half2_t NEG = h2((int)0xFC00FC00);   // (-inf, -inf)
    half2_t a0 = NEG, b0 = NEG, a1 = NEG, b1 = NEG;
    int l = 0;
    for (; l + 2 <= nh; l += 2) {        // uniform (SGPR) trip count
      const int4 qa0 = sp0[l];
      const int4 qb0 = sp0[l + 1];
      const int4 qa1 = sp1[l];
      const int4 qb1 = sp1[l + 1];
      a0 = __builtin_elementwise_max(a0, uPK(qa0, AA, BB, CC, DD, EEv[0]));
      b0 = __builtin_elementwise_max(b0, uPK(qb0, AA, BB, CC, DD, EEv[0]));
      a1 = __builtin_elementwise_max(a1, uPK(qa1, AA, BB, CC, DD, EEv[1]));
      b1 = __builtin_elementwise_max(b1, uPK(qb1, AA, BB, CC, DD, EEv[1]));
    }
    if (l < nh) {
      a0 = __builtin_elementwise_max(a0, uPK(sp0[l], AA, BB, CC, DD, EEv[0]));
      a1 = __builtin_elementwise_max(a1, uPK(sp1[l], AA, BB, CC, DD, EEv[1]));
    }
    const half2_t am0 = __builtin_elementwise_max(a0, b0);
    const half2_t am1 = __builtin_elementwise_max(a1, b1);
    // fmaxf = maxnum: drops a NaN half; n==0 -> -inf, k_apply clamps to sh
    umm[(size_t)(pbase + 0) * 64 + d] = fmaxf((float)am0.x, (float)am0.y);
    umm[(size_t)(pbase + 1) * 64 + d] = fmaxf((float)am1.x, (float)am1.y);
  }

  // ---- epilogue: 10 chains for R2, block reduce, bucketed atomicAdd ----
  #pragma unroll
  for (int i = 0; i < 10; ++i) R2a[i] = dpp_sum64(R2a[i]);

  red[wid][lane] = corrAcc;              // lanes >=54 wrote 0
  if (lane == 63) {
    #pragma unroll
    for (int i = 0; i < 10; ++i) red[wid][64 + i] = R2a[i];
  }
  __syncthreads();
  if (threadIdx.x < NUSED) {
    const int t = threadIdx.x;
    atomicAdd(&buckets[(blockIdx.x & (NBUCKET - 1)) * NPART + t],
              red[0][t] + red[1][t]);
  }
}

// ---------------- Kernel 2: buckets -> per-channel BN scale/shift ----------------

__global__ __launch_bounds__(64) void k_stats(
    const float* __restrict__ buckets, const float* __restrict__ W,
    const float* __restrict__ gamma, const float* __restrict__ beta,
    float* __restrict__ scale, float* __restrict__ shift)
{
  const int d = threadIdx.x;
  __shared__ float Cs[NUSED];
  {
    float s0 = 0.f, s1 = 0.f;
    #pragma unroll
    for (int b = 0; b < NBUCKET; ++b) {
      s0 += buckets[b * NPART + d];
      if (d < NUSED - 64) s1 += buckets[b * NPART + 64 + d];
    }
    Cs[d] = s0;
    if (d < NUSED - 64) Cs[64 + d] = s1;
  }
  __syncthreads();

  // assemble mom1[9], mom2[45]
  float mom1[9];
  #pragma unroll
  for (int q = 0; q < 9; ++q) mom1[q] = Cs[45 + q];
  float mom2[45];
  {
    int k = 0;
    #pragma unroll
    for (int cA = 0; cA < 9; ++cA) {
      #pragma unroll
      for (int cB = cA; cB < 9; ++cB) {
        float v = Cs[k];
        if (cA <= 6 && cB <= 6) {
          const int a = (cA < 4) ? cA : cA - 4;
          const int b = (cB < 4) ? cB : cB - 4;
          const int lo = a < b ? a : b;
          const int hi = a < b ? b : a;
          const int idx = lo * 4 - lo * (lo - 1) / 2 + (hi - lo);
          v += Cs[64 + idx];
        }
        mom2[k] = v;
        ++k;
      }
    }
  }

  float w[9];
  #pragma unroll
  for (int q = 0; q < 9; ++q) w[q] = W[q * 64 + d];
  const float invN = 1.f / ((float)P_N * (float)M_N);
  float mu = 0.f;
  #pragma unroll
  for (int q = 0; q < 9; ++q) mu += mom1[q] * w[q];
  mu *= invN;
  float e2 = 0.f;
  int k = 0;
  #pragma unroll
  for (int cA = 0; cA < 9; ++cA) {
    #pragma unroll
    for (int cB = cA; cB < 9; ++cB) {
      const float t = w[cA] * w[cB] * mom2[k];
      e2 += (cA == cB) ? t : 2.f * t;
      ++k;
    }
  }
  e2 *= invN;
  float var = e2 - mu * mu;
  var = var < 0.f ? 0.f : var;
  const float sc = gamma[d] * rsqrtf(var + 1e-5f);
  const float sh = fmaf(-mu, sc, beta[d]);
  scale[d] = sc;
  shift[d] = sh;
}

// ---------------- Kernel 3: finalize in place ----------------

__global__ __launch_bounds__(256) void k_apply(
    const int* __restrict__ npp, const float* __restrict__ scale,
    const float* __restrict__ shift, float* __restrict__ out)
{
  const int gid = blockIdx.x * 256 + threadIdx.x;   // 0 .. P_N*64/4 - 1
  const int p = gid >> 4;
  const int q = gid & 15;

  float4 u4 = ((const float4*)out)[gid];
  const float4 sc4 = ((const float4*)scale)[q];
  const float4 sh4 = ((const float4*)shift)[q];
  const int n = npp[p];
  const bool has_masked = n < M_N;

  float4 r;
  float t;
  t = fmaf(sc4.x, u4.x, sh4.x); if (has_masked) t = fmaxf(t, sh4.x); r.x = fmaxf(t, 0.f);
  t = fmaf(sc4.y, u4.y, sh4.y); if (has_masked) t = fmaxf(t, sh4.y); r.y = fmaxf(t, 0.f);
  t = fmaf(sc4.z, u4.z, sh4.z); if (has_masked) t = fmaxf(t, sh4.z); r.z = fmaxf(t, 0.f);
  t = fmaf(sc4.w, u4.w, sh4.w); if (has_masked) t = fmaxf(t, sh4.w); r.w = fmaxf(t, 0.f);
  ((float4*)out)[gid] = r;
}

// ---------------- launch ----------------

extern "C" void kernel_launch(void* const* d_in, const int* in_sizes, int n_in,
                              void* d_out, int out_size, void* d_ws, size_t ws_size,
                              hipStream_t stream) {
  const float* px    = (const float*)d_in[0];
  const float* py    = (const float*)d_in[1];
  const float* pz    = (const float*)d_in[2];
  const float* pi    = (const float*)d_in[3];
  const int*   npp   = (const int*)d_in[4];
  const int*   coors = (const int*)d_in[5];
  const float* W     = (const float*)d_in[6];
  const float* gamma = (const float*)d_in[7];
  const float* beta  = (const float*)d_in[8];
  float* out = (float*)d_out;

  float* wsf     = (float*)d_ws;
  float* buckets = wsf;                     // NBUCKET*NPART = 2560 floats
  float* scale   = wsf + 2560;              // 64
  float* shift   = wsf + 2624;              // 64

  k_zero<<<1, 256, 0, stream>>>(buckets);
  k_fused<<<NBF, 128, 0, stream>>>(px, py, pz, pi, npp, coors, W, buckets, out);
  k_stats<<<1, 64, 0, stream>>>(buckets, W, gamma, beta, scale, shift);
  k_apply<<<P_N * 64 / 4 / 256, 256, 0, stream>>>(npp, scale, shift, out);
}